// Round 18
// baseline (128.019 us; speedup 1.0000x reference)
//
#include <hip/hip_runtime.h>
#include <hip/hip_bf16.h>
#include <cstddef>

#define D_MODEL 1024
#define NHEAD   16
#define HD      64
#define BATCH   2
#define SEQ     2048
#define BH      (BATCH*NHEAD)   // 32

typedef short bf16x8 __attribute__((ext_vector_type(8)));
typedef float f32x4  __attribute__((ext_vector_type(4)));

static __device__ __forceinline__ unsigned short f2bf(float f) {
    __hip_bfloat16 h = __float2bfloat16(f);   // RNE
    return __builtin_bit_cast(unsigned short, h);
}
static __device__ __forceinline__ unsigned int pk2(float a, float b) {
    return (unsigned int)f2bf(a) | ((unsigned int)f2bf(b) << 16);
}

// global -> LDS async DMA, 16B per lane: LDS dest = uniform base + lane*16.
#define GLD16(gp, lp) __builtin_amdgcn_global_load_lds( \
    (const __attribute__((address_space(1))) unsigned int*)(gp), \
    (__attribute__((address_space(3))) unsigned int*)(lp), 16, 0, 0)

// ---------------------------------------------------------------------------
// K0: ONE launch for all input prep. Blocks 0..4095: 32x32 transpose tiles
// (w_qkv -> WqT, w_out -> WoT, fp32->bf16). Blocks 4096..5119: linear
// fp32->bf16 of x. (R17: kept — non-attn improved 63.4 -> 61.6 us.)
// ---------------------------------------------------------------------------
__global__ __launch_bounds__(256) void cvt_all_kernel(
    const float* __restrict__ x, const float* __restrict__ Wq,
    const float* __restrict__ Wo, unsigned short* __restrict__ Xb,
    unsigned short* __restrict__ WqT, unsigned short* __restrict__ WoT)
{
    __shared__ float T[32][33];
    const int bid = blockIdx.x;
    const int tid = threadIdx.x;
    if (bid < 4096) {
        const int bx = bid & 127;         // n-tile
        const int k0 = (bid >> 7) * 32;   // k-tile
        const float* W; unsigned short* WT; int N, n0;
        if (bx < 96) { W = Wq; WT = WqT; N = 3072; n0 = bx*32; }
        else         { W = Wo; WT = WoT; N = 1024; n0 = (bx-96)*32; }
        const int r  = tid >> 3;          // 0..31
        const int cg = tid & 7;           // 0..7
        float4 v = *(const float4*)&W[(size_t)(k0 + r)*N + n0 + cg*4];
        T[r][cg*4+0] = v.x; T[r][cg*4+1] = v.y;
        T[r][cg*4+2] = v.z; T[r][cg*4+3] = v.w;
        __syncthreads();
        uint2 w;
        w.x = pk2(T[cg*4+0][r], T[cg*4+1][r]);
        w.y = pk2(T[cg*4+2][r], T[cg*4+3][r]);
        *(uint2*)&WT[(size_t)(n0 + r)*1024 + k0 + cg*4] = w;
    } else {
        const int n8 = (BATCH*SEQ*D_MODEL)/8;
        const int stride = 1024 * 256;
        for (int i = (bid - 4096)*256 + tid; i < n8; i += stride) {
            const float4 a = ((const float4*)x)[i*2];
            const float4 b = ((const float4*)x)[i*2+1];
            uint4 w;
            w.x = pk2(a.x, a.y); w.y = pk2(a.z, a.w);
            w.z = pk2(b.x, b.y); w.w = pk2(b.z, b.w);
            ((uint4*)Xb)[i] = w;
        }
    }
}

// ---------------------------------------------------------------------------
// K1/K3 v2: bf16 MFMA GEMM with global_load_lds staging. Unchanged (R15,
// bit-exact).
// ---------------------------------------------------------------------------
template<int NN, bool QKV>
__global__ __launch_bounds__(256, 2) void gemm_bf16_kernel(
    const unsigned short* __restrict__ A, const unsigned short* __restrict__ BT,
    unsigned short* __restrict__ Qo, unsigned short* __restrict__ Ko,
    unsigned short* __restrict__ Vo, float* __restrict__ Cf)
{
    __shared__ __align__(16) unsigned short As[128*32];
    __shared__ __align__(16) unsigned short Bs[128*32];

    const int tid  = threadIdx.x;
    const int wv   = tid >> 6;
    const int l    = tid & 63;
    const int ln   = l & 15;
    const int lg   = l >> 4;
    const int wrow = (wv >> 1) * 64;
    const int wcol = (wv & 1) * 64;
    const int mtile = blockIdx.y * 128;
    const int ntile = blockIdx.x * 128;

    const int c0 = wv*128 + l;
    const int c1 = c0 + 64;
    const int r0 = c0 >> 2, ks0 = ((c0 & 3) ^ ((r0 + (r0 >> 2)) & 3)) * 8;
    const int r1 = c1 >> 2, ks1 = ((c1 & 3) ^ ((r1 + (r1 >> 2)) & 3)) * 8;
    const size_t gA0 = (size_t)(mtile + r0)*1024 + ks0;
    const size_t gA1 = (size_t)(mtile + r1)*1024 + ks1;
    const size_t gB0 = (size_t)(ntile + r0)*1024 + ks0;
    const size_t gB1 = (size_t)(ntile + r1)*1024 + ks1;
    unsigned short* lA0 = &As[(wv*128     ) * 8];
    unsigned short* lA1 = &As[(wv*128 + 64) * 8];
    unsigned short* lB0 = &Bs[(wv*128     ) * 8];
    unsigned short* lB1 = &Bs[(wv*128 + 64) * 8];

    const int sw = ((lg ^ ((ln + (ln >> 2)) & 3))) * 8;

    f32x4 acc[4][4] = {};

    for (int kb = 0; kb < 32; ++kb) {
        const int koff = kb * 32;
        GLD16(A  + gA0 + koff, lA0);
        GLD16(A  + gA1 + koff, lA1);
        GLD16(BT + gB0 + koff, lB0);
        GLD16(BT + gB1 + koff, lB1);
        __syncthreads();
        bf16x8 af[4], bf[4];
        #pragma unroll
        for (int i = 0; i < 4; ++i)
            af[i] = *(const bf16x8*)&As[(wrow + i*16 + ln)*32 + sw];
        #pragma unroll
        for (int j = 0; j < 4; ++j)
            bf[j] = *(const bf16x8*)&Bs[(wcol + j*16 + ln)*32 + sw];
        #pragma unroll
        for (int i = 0; i < 4; ++i)
            #pragma unroll
            for (int j = 0; j < 4; ++j)
                acc[i][j] = __builtin_amdgcn_mfma_f32_16x16x32_bf16(af[i], bf[j], acc[i][j], 0, 0, 0);
        __syncthreads();
    }

    #pragma unroll
    for (int i = 0; i < 4; ++i) {
        #pragma unroll
        for (int r = 0; r < 4; ++r) {
            const int mm = mtile + wrow + i*16 + lg*4 + r;
            if constexpr (QKV) {
                const int bb = mm >> 11;
                const int ss = mm & 2047;
                #pragma unroll
                for (int j = 0; j < 4; ++j) {
                    const int cb  = ntile + wcol + j*16 + ln;
                    const int wch = cb >> 10;
                    const int rem = cb & 1023;
                    const int h   = rem >> 6;
                    const int dd  = rem & 63;
                    unsigned short* dstBase = (wch == 0) ? Qo : (wch == 1) ? Ko : Vo;
                    dstBase[((size_t)(bb*NHEAD + h)*SEQ + ss)*HD + dd] = f2bf(acc[i][j][r]);
                }
            } else {
                #pragma unroll
                for (int j = 0; j < 4; ++j) {
                    const int cb = ntile + wcol + j*16 + ln;
                    Cf[(size_t)mm*NN + cb] = acc[i][j][r];
                }
            }
        }
    }
}

// ---------------------------------------------------------------------------
// K2 v12: v10 EXACTLY (R16, 61.4 us — v11's exp2/mask-skip REGRESSED to 65,
// reverted) + T5 s_setprio(1) around the two MFMA clusters. Guide m191:
// +4-7% on attn when co-resident blocks are phase-desynced (ours: 2
// independent blocks/CU drift apart) — favors MFMA-entering waves over
// staging waves. Zero structural risk.
// ---------------------------------------------------------------------------
__global__ __launch_bounds__(256, 2) void attn_kernel(
    const unsigned short* __restrict__ Qb, const unsigned short* __restrict__ Kb,
    const unsigned short* __restrict__ Vb, unsigned short* __restrict__ AO)
{
    __shared__ __align__(16) unsigned short Ks[2][64][72];  // keys x dims(+pad)
    __shared__ __align__(16) unsigned short Vt[2][64][72];  // dims x keys(+pad)
    __shared__ __align__(16) unsigned short Pl[4][16][76];  // per-wave P^T

    const int tid = threadIdx.x;
    const int wv  = tid >> 6;
    const int l   = tid & 63;
    const int ln  = l & 15;
    const int lg  = l >> 4;
    const int bh  = blockIdx.y;
    const int bx  = blockIdx.x;          // 0..15
    const int qtA = 31 - bx;
    const int qtB = bx;
    const int nTA = qtA + 1;
    const int nT  = nTA + qtB + 1;       // 33 always

    const unsigned short* Qbh = Qb + (size_t)bh*SEQ*HD;
    const unsigned short* Kbh = Kb + (size_t)bh*SEQ*HD;
    const unsigned short* Vbh = Vb + (size_t)bh*SEQ*HD;

    const int s_kl = tid >> 3;
    const int s_d0 = (tid & 7) << 3;
    const int s_dg = tid >> 4;
    const int s_kp = (tid & 15) << 1;

    auto ktOf = [&](int t) { return (t < nTA ? t : t - nTA) * 64; };

    // T14 split: global->regs (issue early) vs regs->LDS (write late)
    uint4 rk0, rk1;
    uint2 rva0, rvb0, rva1, rvb1;
    auto load_tile = [&](int kt) {
        rk0  = *(const uint4*)&Kbh[(size_t)(kt + s_kl     )*HD + s_d0];
        rk1  = *(const uint4*)&Kbh[(size_t)(kt + s_kl + 32)*HD + s_d0];
        rva0 = *(const uint2*)&Vbh[(size_t)(kt + s_kp     )*HD + s_dg*4];
        rvb0 = *(const uint2*)&Vbh[(size_t)(kt + s_kp + 1 )*HD + s_dg*4];
        rva1 = *(const uint2*)&Vbh[(size_t)(kt + s_kp + 32)*HD + s_dg*4];
        rvb1 = *(const uint2*)&Vbh[(size_t)(kt + s_kp + 33)*HD + s_dg*4];
    };
    auto write_tile = [&](int nb) {
        *(uint4*)&Ks[nb][s_kl     ][s_d0] = rk0;
        *(uint4*)&Ks[nb][s_kl + 32][s_d0] = rk1;
        *(unsigned int*)&Vt[nb][s_dg*4+0][s_kp]    = (rva0.x & 0xffffu) | (rvb0.x << 16);
        *(unsigned int*)&Vt[nb][s_dg*4+1][s_kp]    = (rva0.x >> 16)     | (rvb0.x & 0xffff0000u);
        *(unsigned int*)&Vt[nb][s_dg*4+2][s_kp]    = (rva0.y & 0xffffu) | (rvb0.y << 16);
        *(unsigned int*)&Vt[nb][s_dg*4+3][s_kp]    = (rva0.y >> 16)     | (rvb0.y & 0xffff0000u);
        *(unsigned int*)&Vt[nb][s_dg*4+0][s_kp+32] = (rva1.x & 0xffffu) | (rvb1.x << 16);
        *(unsigned int*)&Vt[nb][s_dg*4+1][s_kp+32] = (rva1.x >> 16)     | (rvb1.x & 0xffff0000u);
        *(unsigned int*)&Vt[nb][s_dg*4+2][s_kp+32] = (rva1.y & 0xffffu) | (rvb1.y << 16);
        *(unsigned int*)&Vt[nb][s_dg*4+3][s_kp+32] = (rva1.y >> 16)     | (rvb1.y & 0xffff0000u);
    };

    int qrow0 = qtA*64 + wv*16;
    bf16x8 q0 = *(const bf16x8*)&Qbh[(size_t)(qrow0 + ln)*HD + lg*8];
    bf16x8 q1 = *(const bf16x8*)&Qbh[(size_t)(qrow0 + ln)*HD + 32 + lg*8];

    f32x4 o[4] = {};
    float m = -1e30f, lsum = 0.f;

    auto epilogue = [&](int qr0) {
        const int bb = bh >> 4;
        const int h  = bh & 15;
        const float inv = 1.f / lsum;
        const size_t base = ((size_t)bb*SEQ + qr0 + ln)*D_MODEL + h*HD + lg*4;
        #pragma unroll
        for (int f = 0; f < 4; ++f) {
            uint2 w;
            w.x = pk2(o[f][0]*inv, o[f][1]*inv);
            w.y = pk2(o[f][2]*inv, o[f][3]*inv);
            *(uint2*)&AO[base + f*16] = w;
        }
    };

    // prologue: tile 0 staged synchronously; tile 1 loads issued early
    load_tile(0);
    write_tile(0);
    if (nT > 1) load_tile(ktOf(1));

    for (int t = 0; t < nT; ++t) {
        __syncthreads();                     // publishes buf[t&1]
        const int buf = t & 1;
        const int kt = ktOf(t);

        // ---- QK^T swapped: S^T(64keys x 16q)
        f32x4 s[4];
        __builtin_amdgcn_s_setprio(1);
        #pragma unroll
        for (int g = 0; g < 4; ++g) {
            bf16x8 ka = *(const bf16x8*)&Ks[buf][g*16 + ln][lg*8];
            bf16x8 kb = *(const bf16x8*)&Ks[buf][g*16 + ln][32 + lg*8];
            f32x4 sg = {};
            sg = __builtin_amdgcn_mfma_f32_16x16x32_bf16(ka, q0, sg, 0, 0, 0);
            sg = __builtin_amdgcn_mfma_f32_16x16x32_bf16(kb, q1, sg, 0, 0, 0);
            s[g] = sg;
        }
        __builtin_amdgcn_s_setprio(0);

        const int qg = qrow0 + ln;
        const int kbase = kt + lg*4;
        float mx = -1e30f;
        #pragma unroll
        for (int g = 0; g < 4; ++g) {
            #pragma unroll
            for (int r = 0; r < 4; ++r) {
                float v = s[g][r] * 0.125f;
                v = (kbase + g*16 + r > qg) ? -1e30f : v;
                s[g][r] = v;
                mx = fmaxf(mx, v);
            }
        }
        mx = fmaxf(mx, __shfl_xor(mx, 16));
        mx = fmaxf(mx, __shfl_xor(mx, 32));

        if (__any(mx > m)) {
            const float mnew = fmaxf(m, mx);
            const float alpha = __expf(m - mnew);
            m = mnew;
            lsum *= alpha;
            #pragma unroll
            for (int f = 0; f < 4; ++f)
                #pragma unroll
                for (int r = 0; r < 4; ++r) o[f][r] *= alpha;
        }
        float ps = 0.f;
        #pragma unroll
        for (int g = 0; g < 4; ++g) {
            #pragma unroll
            for (int r = 0; r < 4; ++r) {
                const float e = __expf(s[g][r] - m);
                s[g][r] = e;
                ps += e;
            }
        }
        ps += __shfl_xor(ps, 16);
        ps += __shfl_xor(ps, 32);
        lsum += ps;

        #pragma unroll
        for (int g = 0; g < 4; ++g) {
            unsigned long long w =
                (unsigned long long)pk2(s[g][0], s[g][1]) |
                ((unsigned long long)pk2(s[g][2], s[g][3]) << 32);
            *(unsigned long long*)&Pl[wv][ln][g*16 + lg*4] = w;
        }
        bf16x8 pb0 = *(const bf16x8*)&Pl[wv][ln][lg*8];
        bf16x8 pb1 = *(const bf16x8*)&Pl[wv][ln][32 + lg*8];

        __builtin_amdgcn_s_setprio(1);
        #pragma unroll
        for (int f = 0; f < 4; ++f) {
            bf16x8 v0 = *(const bf16x8*)&Vt[buf][f*16 + ln][lg*8];
            bf16x8 v1 = *(const bf16x8*)&Vt[buf][f*16 + ln][32 + lg*8];
            o[f] = __builtin_amdgcn_mfma_f32_16x16x32_bf16(v0, pb0, o[f], 0, 0, 0);
            o[f] = __builtin_amdgcn_mfma_f32_16x16x32_bf16(v1, pb1, o[f], 0, 0, 0);
        }
        __builtin_amdgcn_s_setprio(0);

        // ---- late stage write for t+1, then issue loads for t+2
        if (t + 1 < nT) {
            write_tile(buf ^ 1);
            if (t + 2 < nT) load_tile(ktOf(t + 2));
        }

        // ---- phase boundary: flush q-tile A, reset for q-tile B
        if (t == nTA - 1) {
            epilogue(qrow0);
            qrow0 = qtB*64 + wv*16;
            q0 = *(const bf16x8*)&Qbh[(size_t)(qrow0 + ln)*HD + lg*8];
            q1 = *(const bf16x8*)&Qbh[(size_t)(qrow0 + ln)*HD + 32 + lg*8];
            m = -1e30f; lsum = 0.f;
            #pragma unroll
            for (int f = 0; f < 4; ++f)
                #pragma unroll
                for (int r = 0; r < 4; ++r) o[f][r] = 0.f;
        }
    }
    epilogue(qrow0);   // q-tile B
}

// ---------------------------------------------------------------------------
extern "C" void kernel_launch(void* const* d_in, const int* in_sizes, int n_in,
                              void* d_out, int out_size, void* d_ws, size_t ws_size,
                              hipStream_t stream)
{
    const float* x     = (const float*)d_in[0];   // (2,2048,1024)
    const float* w_qkv = (const float*)d_in[1];   // (1024,3072)
    const float* w_out = (const float*)d_in[2];   // (1024,1024)
    float* out = (float*)d_out;                   // (2,2048,1024)

    const size_t nX  = (size_t)BATCH*SEQ*D_MODEL;      // 4 Mi
    const size_t nWq = (size_t)D_MODEL*3*D_MODEL;      // 3 Mi
    const size_t nWo = (size_t)D_MODEL*D_MODEL;        // 1 Mi
    const size_t per = (size_t)BH * SEQ * HD;          // 4 Mi

    unsigned short* Xb   = (unsigned short*)d_ws;      // bf16 x (M x K)
    unsigned short* WqT  = Xb   + nX;                  // bf16 w_qkv^T
    unsigned short* WoT  = WqT  + nWq;                 // bf16 w_out^T
    unsigned short* Qb   = WoT  + nWo;
    unsigned short* Kb   = Qb + per;
    unsigned short* Vb   = Kb + per;
    unsigned short* AOb  = Vb + per;                   // bf16 (B,S,D)

    // all input prep in one launch: 4096 transpose blocks + 1024 cvt blocks
    cvt_all_kernel<<<5120, 256, 0, stream>>>(x, w_qkv, w_out, Xb, WqT, WoT);

    gemm_bf16_kernel<3*D_MODEL, true><<<dim3(24, 32), 256, 0, stream>>>(
        Xb, WqT, Qb, Kb, Vb, nullptr);
    attn_kernel<<<dim3(16, BH), 256, 0, stream>>>(Qb, Kb, Vb, AOb);
    gemm_bf16_kernel<D_MODEL, false><<<dim3(8, 32), 256, 0, stream>>>(
        AOb, WoT, nullptr, nullptr, nullptr, out);
}

// Round 19
// 122.895 us; speedup vs baseline: 1.0417x; 1.0417x over previous
//
#include <hip/hip_runtime.h>
#include <hip/hip_bf16.h>
#include <cstddef>

#define D_MODEL 1024
#define NHEAD   16
#define HD      64
#define BATCH   2
#define SEQ     2048
#define BH      (BATCH*NHEAD)   // 32

typedef short bf16x8 __attribute__((ext_vector_type(8)));
typedef float f32x4  __attribute__((ext_vector_type(4)));

static __device__ __forceinline__ unsigned short f2bf(float f) {
    __hip_bfloat16 h = __float2bfloat16(f);   // RNE
    return __builtin_bit_cast(unsigned short, h);
}
static __device__ __forceinline__ unsigned int pk2(float a, float b) {
    return (unsigned int)f2bf(a) | ((unsigned int)f2bf(b) << 16);
}

// global -> LDS async DMA, 16B per lane: LDS dest = uniform base + lane*16.
#define GLD16(gp, lp) __builtin_amdgcn_global_load_lds( \
    (const __attribute__((address_space(1))) unsigned int*)(gp), \
    (__attribute__((address_space(3))) unsigned int*)(lp), 16, 0, 0)

// ---------------------------------------------------------------------------
// K0: ONE launch for all input prep. Blocks 0..4095: 32x32 transpose tiles
// (w_qkv -> WqT, w_out -> WoT, fp32->bf16). Blocks 4096..5119: linear
// fp32->bf16 of x. (R17/R18: non-attn 63.4 -> ~62 us; kept.)
// ---------------------------------------------------------------------------
__global__ __launch_bounds__(256) void cvt_all_kernel(
    const float* __restrict__ x, const float* __restrict__ Wq,
    const float* __restrict__ Wo, unsigned short* __restrict__ Xb,
    unsigned short* __restrict__ WqT, unsigned short* __restrict__ WoT)
{
    __shared__ float T[32][33];
    const int bid = blockIdx.x;
    const int tid = threadIdx.x;
    if (bid < 4096) {
        const int bx = bid & 127;         // n-tile
        const int k0 = (bid >> 7) * 32;   // k-tile
        const float* W; unsigned short* WT; int N, n0;
        if (bx < 96) { W = Wq; WT = WqT; N = 3072; n0 = bx*32; }
        else         { W = Wo; WT = WoT; N = 1024; n0 = (bx-96)*32; }
        const int r  = tid >> 3;          // 0..31
        const int cg = tid & 7;           // 0..7
        float4 v = *(const float4*)&W[(size_t)(k0 + r)*N + n0 + cg*4];
        T[r][cg*4+0] = v.x; T[r][cg*4+1] = v.y;
        T[r][cg*4+2] = v.z; T[r][cg*4+3] = v.w;
        __syncthreads();
        uint2 w;
        w.x = pk2(T[cg*4+0][r], T[cg*4+1][r]);
        w.y = pk2(T[cg*4+2][r], T[cg*4+3][r]);
        *(uint2*)&WT[(size_t)(n0 + r)*1024 + k0 + cg*4] = w;
    } else {
        const int n8 = (BATCH*SEQ*D_MODEL)/8;
        const int stride = 1024 * 256;
        for (int i = (bid - 4096)*256 + tid; i < n8; i += stride) {
            const float4 a = ((const float4*)x)[i*2];
            const float4 b = ((const float4*)x)[i*2+1];
            uint4 w;
            w.x = pk2(a.x, a.y); w.y = pk2(a.z, a.w);
            w.z = pk2(b.x, b.y); w.w = pk2(b.z, b.w);
            ((uint4*)Xb)[i] = w;
        }
    }
}

// ---------------------------------------------------------------------------
// K1/K3 v2: bf16 MFMA GEMM with global_load_lds staging. Unchanged (R15,
// bit-exact).
// ---------------------------------------------------------------------------
template<int NN, bool QKV>
__global__ __launch_bounds__(256, 2) void gemm_bf16_kernel(
    const unsigned short* __restrict__ A, const unsigned short* __restrict__ BT,
    unsigned short* __restrict__ Qo, unsigned short* __restrict__ Ko,
    unsigned short* __restrict__ Vo, float* __restrict__ Cf)
{
    __shared__ __align__(16) unsigned short As[128*32];
    __shared__ __align__(16) unsigned short Bs[128*32];

    const int tid  = threadIdx.x;
    const int wv   = tid >> 6;
    const int l    = tid & 63;
    const int ln   = l & 15;
    const int lg   = l >> 4;
    const int wrow = (wv >> 1) * 64;
    const int wcol = (wv & 1) * 64;
    const int mtile = blockIdx.y * 128;
    const int ntile = blockIdx.x * 128;

    const int c0 = wv*128 + l;
    const int c1 = c0 + 64;
    const int r0 = c0 >> 2, ks0 = ((c0 & 3) ^ ((r0 + (r0 >> 2)) & 3)) * 8;
    const int r1 = c1 >> 2, ks1 = ((c1 & 3) ^ ((r1 + (r1 >> 2)) & 3)) * 8;
    const size_t gA0 = (size_t)(mtile + r0)*1024 + ks0;
    const size_t gA1 = (size_t)(mtile + r1)*1024 + ks1;
    const size_t gB0 = (size_t)(ntile + r0)*1024 + ks0;
    const size_t gB1 = (size_t)(ntile + r1)*1024 + ks1;
    unsigned short* lA0 = &As[(wv*128     ) * 8];
    unsigned short* lA1 = &As[(wv*128 + 64) * 8];
    unsigned short* lB0 = &Bs[(wv*128     ) * 8];
    unsigned short* lB1 = &Bs[(wv*128 + 64) * 8];

    const int sw = ((lg ^ ((ln + (ln >> 2)) & 3))) * 8;

    f32x4 acc[4][4] = {};

    for (int kb = 0; kb < 32; ++kb) {
        const int koff = kb * 32;
        GLD16(A  + gA0 + koff, lA0);
        GLD16(A  + gA1 + koff, lA1);
        GLD16(BT + gB0 + koff, lB0);
        GLD16(BT + gB1 + koff, lB1);
        __syncthreads();
        bf16x8 af[4], bf[4];
        #pragma unroll
        for (int i = 0; i < 4; ++i)
            af[i] = *(const bf16x8*)&As[(wrow + i*16 + ln)*32 + sw];
        #pragma unroll
        for (int j = 0; j < 4; ++j)
            bf[j] = *(const bf16x8*)&Bs[(wcol + j*16 + ln)*32 + sw];
        #pragma unroll
        for (int i = 0; i < 4; ++i)
            #pragma unroll
            for (int j = 0; j < 4; ++j)
                acc[i][j] = __builtin_amdgcn_mfma_f32_16x16x32_bf16(af[i], bf[j], acc[i][j], 0, 0, 0);
        __syncthreads();
    }

    #pragma unroll
    for (int i = 0; i < 4; ++i) {
        #pragma unroll
        for (int r = 0; r < 4; ++r) {
            const int mm = mtile + wrow + i*16 + lg*4 + r;
            if constexpr (QKV) {
                const int bb = mm >> 11;
                const int ss = mm & 2047;
                #pragma unroll
                for (int j = 0; j < 4; ++j) {
                    const int cb  = ntile + wcol + j*16 + ln;
                    const int wch = cb >> 10;
                    const int rem = cb & 1023;
                    const int h   = rem >> 6;
                    const int dd  = rem & 63;
                    unsigned short* dstBase = (wch == 0) ? Qo : (wch == 1) ? Ko : Vo;
                    dstBase[((size_t)(bb*NHEAD + h)*SEQ + ss)*HD + dd] = f2bf(acc[i][j][r]);
                }
            } else {
                #pragma unroll
                for (int j = 0; j < 4; ++j) {
                    const int cb = ntile + wcol + j*16 + ln;
                    Cf[(size_t)mm*NN + cb] = acc[i][j][r];
                }
            }
        }
    }
}

// ---------------------------------------------------------------------------
// K2 v13 = v10 EXACTLY (the 61.4 us kernel from R16's bench). Both R17's
// exp2/mask-skip (+3.6us) and R18's setprio (+4.5us) perturbations REGRESSED
// — v10's compiler schedule is a local optimum; reverted byte-for-byte.
// Structure: swapped QK^T (S^T = mfma(K,Q), per-lane scalar m/lsum, 2-level
// shuffles), KVBLK=64, paired q-tiles (33 tiles/block, perfectly balanced),
// T14 async-STAGE split (loads t+2 issued under compute of t+1), defer-max.
// ---------------------------------------------------------------------------
__global__ __launch_bounds__(256, 2) void attn_kernel(
    const unsigned short* __restrict__ Qb, const unsigned short* __restrict__ Kb,
    const unsigned short* __restrict__ Vb, unsigned short* __restrict__ AO)
{
    __shared__ __align__(16) unsigned short Ks[2][64][72];  // keys x dims(+pad)
    __shared__ __align__(16) unsigned short Vt[2][64][72];  // dims x keys(+pad)
    __shared__ __align__(16) unsigned short Pl[4][16][76];  // per-wave P^T

    const int tid = threadIdx.x;
    const int wv  = tid >> 6;
    const int l   = tid & 63;
    const int ln  = l & 15;
    const int lg  = l >> 4;
    const int bh  = blockIdx.y;
    const int bx  = blockIdx.x;          // 0..15
    const int qtA = 31 - bx;
    const int qtB = bx;
    const int nTA = qtA + 1;
    const int nT  = nTA + qtB + 1;       // 33 always

    const unsigned short* Qbh = Qb + (size_t)bh*SEQ*HD;
    const unsigned short* Kbh = Kb + (size_t)bh*SEQ*HD;
    const unsigned short* Vbh = Vb + (size_t)bh*SEQ*HD;

    const int s_kl = tid >> 3;
    const int s_d0 = (tid & 7) << 3;
    const int s_dg = tid >> 4;
    const int s_kp = (tid & 15) << 1;

    auto ktOf = [&](int t) { return (t < nTA ? t : t - nTA) * 64; };

    // T14 split: global->regs (issue early) vs regs->LDS (write late)
    uint4 rk0, rk1;
    uint2 rva0, rvb0, rva1, rvb1;
    auto load_tile = [&](int kt) {
        rk0  = *(const uint4*)&Kbh[(size_t)(kt + s_kl     )*HD + s_d0];
        rk1  = *(const uint4*)&Kbh[(size_t)(kt + s_kl + 32)*HD + s_d0];
        rva0 = *(const uint2*)&Vbh[(size_t)(kt + s_kp     )*HD + s_dg*4];
        rvb0 = *(const uint2*)&Vbh[(size_t)(kt + s_kp + 1 )*HD + s_dg*4];
        rva1 = *(const uint2*)&Vbh[(size_t)(kt + s_kp + 32)*HD + s_dg*4];
        rvb1 = *(const uint2*)&Vbh[(size_t)(kt + s_kp + 33)*HD + s_dg*4];
    };
    auto write_tile = [&](int nb) {
        *(uint4*)&Ks[nb][s_kl     ][s_d0] = rk0;
        *(uint4*)&Ks[nb][s_kl + 32][s_d0] = rk1;
        *(unsigned int*)&Vt[nb][s_dg*4+0][s_kp]    = (rva0.x & 0xffffu) | (rvb0.x << 16);
        *(unsigned int*)&Vt[nb][s_dg*4+1][s_kp]    = (rva0.x >> 16)     | (rvb0.x & 0xffff0000u);
        *(unsigned int*)&Vt[nb][s_dg*4+2][s_kp]    = (rva0.y & 0xffffu) | (rvb0.y << 16);
        *(unsigned int*)&Vt[nb][s_dg*4+3][s_kp]    = (rva0.y >> 16)     | (rvb0.y & 0xffff0000u);
        *(unsigned int*)&Vt[nb][s_dg*4+0][s_kp+32] = (rva1.x & 0xffffu) | (rvb1.x << 16);
        *(unsigned int*)&Vt[nb][s_dg*4+1][s_kp+32] = (rva1.x >> 16)     | (rvb1.x & 0xffff0000u);
        *(unsigned int*)&Vt[nb][s_dg*4+2][s_kp+32] = (rva1.y & 0xffffu) | (rvb1.y << 16);
        *(unsigned int*)&Vt[nb][s_dg*4+3][s_kp+32] = (rva1.y >> 16)     | (rvb1.y & 0xffff0000u);
    };

    int qrow0 = qtA*64 + wv*16;
    bf16x8 q0 = *(const bf16x8*)&Qbh[(size_t)(qrow0 + ln)*HD + lg*8];
    bf16x8 q1 = *(const bf16x8*)&Qbh[(size_t)(qrow0 + ln)*HD + 32 + lg*8];

    f32x4 o[4] = {};
    float m = -1e30f, lsum = 0.f;

    auto epilogue = [&](int qr0) {
        const int bb = bh >> 4;
        const int h  = bh & 15;
        const float inv = 1.f / lsum;
        const size_t base = ((size_t)bb*SEQ + qr0 + ln)*D_MODEL + h*HD + lg*4;
        #pragma unroll
        for (int f = 0; f < 4; ++f) {
            uint2 w;
            w.x = pk2(o[f][0]*inv, o[f][1]*inv);
            w.y = pk2(o[f][2]*inv, o[f][3]*inv);
            *(uint2*)&AO[base + f*16] = w;
        }
    };

    // prologue: tile 0 staged synchronously; tile 1 loads issued early
    load_tile(0);
    write_tile(0);
    if (nT > 1) load_tile(ktOf(1));

    for (int t = 0; t < nT; ++t) {
        __syncthreads();                     // publishes buf[t&1]
        const int buf = t & 1;
        const int kt = ktOf(t);

        // ---- QK^T swapped: S^T(64keys x 16q)
        f32x4 s[4];
        #pragma unroll
        for (int g = 0; g < 4; ++g) {
            bf16x8 ka = *(const bf16x8*)&Ks[buf][g*16 + ln][lg*8];
            bf16x8 kb = *(const bf16x8*)&Ks[buf][g*16 + ln][32 + lg*8];
            f32x4 sg = {};
            sg = __builtin_amdgcn_mfma_f32_16x16x32_bf16(ka, q0, sg, 0, 0, 0);
            sg = __builtin_amdgcn_mfma_f32_16x16x32_bf16(kb, q1, sg, 0, 0, 0);
            s[g] = sg;
        }

        const int qg = qrow0 + ln;
        const int kbase = kt + lg*4;
        float mx = -1e30f;
        #pragma unroll
        for (int g = 0; g < 4; ++g) {
            #pragma unroll
            for (int r = 0; r < 4; ++r) {
                float v = s[g][r] * 0.125f;
                v = (kbase + g*16 + r > qg) ? -1e30f : v;
                s[g][r] = v;
                mx = fmaxf(mx, v);
            }
        }
        mx = fmaxf(mx, __shfl_xor(mx, 16));
        mx = fmaxf(mx, __shfl_xor(mx, 32));

        if (__any(mx > m)) {
            const float mnew = fmaxf(m, mx);
            const float alpha = __expf(m - mnew);
            m = mnew;
            lsum *= alpha;
            #pragma unroll
            for (int f = 0; f < 4; ++f)
                #pragma unroll
                for (int r = 0; r < 4; ++r) o[f][r] *= alpha;
        }
        float ps = 0.f;
        #pragma unroll
        for (int g = 0; g < 4; ++g) {
            #pragma unroll
            for (int r = 0; r < 4; ++r) {
                const float e = __expf(s[g][r] - m);
                s[g][r] = e;
                ps += e;
            }
        }
        ps += __shfl_xor(ps, 16);
        ps += __shfl_xor(ps, 32);
        lsum += ps;

        #pragma unroll
        for (int g = 0; g < 4; ++g) {
            unsigned long long w =
                (unsigned long long)pk2(s[g][0], s[g][1]) |
                ((unsigned long long)pk2(s[g][2], s[g][3]) << 32);
            *(unsigned long long*)&Pl[wv][ln][g*16 + lg*4] = w;
        }
        bf16x8 pb0 = *(const bf16x8*)&Pl[wv][ln][lg*8];
        bf16x8 pb1 = *(const bf16x8*)&Pl[wv][ln][32 + lg*8];

        #pragma unroll
        for (int f = 0; f < 4; ++f) {
            bf16x8 v0 = *(const bf16x8*)&Vt[buf][f*16 + ln][lg*8];
            bf16x8 v1 = *(const bf16x8*)&Vt[buf][f*16 + ln][32 + lg*8];
            o[f] = __builtin_amdgcn_mfma_f32_16x16x32_bf16(v0, pb0, o[f], 0, 0, 0);
            o[f] = __builtin_amdgcn_mfma_f32_16x16x32_bf16(v1, pb1, o[f], 0, 0, 0);
        }

        // ---- late stage write for t+1, then issue loads for t+2
        if (t + 1 < nT) {
            write_tile(buf ^ 1);
            if (t + 2 < nT) load_tile(ktOf(t + 2));
        }

        // ---- phase boundary: flush q-tile A, reset for q-tile B
        if (t == nTA - 1) {
            epilogue(qrow0);
            qrow0 = qtB*64 + wv*16;
            q0 = *(const bf16x8*)&Qbh[(size_t)(qrow0 + ln)*HD + lg*8];
            q1 = *(const bf16x8*)&Qbh[(size_t)(qrow0 + ln)*HD + 32 + lg*8];
            m = -1e30f; lsum = 0.f;
            #pragma unroll
            for (int f = 0; f < 4; ++f)
                #pragma unroll
                for (int r = 0; r < 4; ++r) o[f][r] = 0.f;
        }
    }
    epilogue(qrow0);   // q-tile B
}

// ---------------------------------------------------------------------------
extern "C" void kernel_launch(void* const* d_in, const int* in_sizes, int n_in,
                              void* d_out, int out_size, void* d_ws, size_t ws_size,
                              hipStream_t stream)
{
    const float* x     = (const float*)d_in[0];   // (2,2048,1024)
    const float* w_qkv = (const float*)d_in[1];   // (1024,3072)
    const float* w_out = (const float*)d_in[2];   // (1024,1024)
    float* out = (float*)d_out;                   // (2,2048,1024)

    const size_t nX  = (size_t)BATCH*SEQ*D_MODEL;      // 4 Mi
    const size_t nWq = (size_t)D_MODEL*3*D_MODEL;      // 3 Mi
    const size_t nWo = (size_t)D_MODEL*D_MODEL;        // 1 Mi
    const size_t per = (size_t)BH * SEQ * HD;          // 4 Mi

    unsigned short* Xb   = (unsigned short*)d_ws;      // bf16 x (M x K)
    unsigned short* WqT  = Xb   + nX;                  // bf16 w_qkv^T
    unsigned short* WoT  = WqT  + nWq;                 // bf16 w_out^T
    unsigned short* Qb   = WoT  + nWo;
    unsigned short* Kb   = Qb + per;
    unsigned short* Vb   = Kb + per;
    unsigned short* AOb  = Vb + per;                   // bf16 (B,S,D)

    // all input prep in one launch: 4096 transpose blocks + 1024 cvt blocks
    cvt_all_kernel<<<5120, 256, 0, stream>>>(x, w_qkv, w_out, Xb, WqT, WoT);

    gemm_bf16_kernel<3*D_MODEL, true><<<dim3(24, 32), 256, 0, stream>>>(
        Xb, WqT, Qb, Kb, Vb, nullptr);
    attn_kernel<<<dim3(16, BH), 256, 0, stream>>>(Qb, Kb, Vb, AOb);
    gemm_bf16_kernel<D_MODEL, false><<<dim3(8, 32), 256, 0, stream>>>(
        AOb, WoT, nullptr, nullptr, nullptr, out);
}